// Round 1
// 217.372 us; speedup vs baseline: 1.0119x; 1.0119x over previous
//
#include <hip/hip_runtime.h>

// GraphEmbedder: B=8, C=64, G=65536, 4 layers of y=lrelu(W@[x; x-x0]), then max over G.
// Identity: W@[x; x-x0] = Wa@x - Wb@x0, Wa = W[:,:64]+W[:,64:], Wb = W[:,64:].
// R8: ge_main was LDS-bound (48 ds_read_b128/nt/wave = ~31 us kernel-total vs 22 us HBM floor).
//  - weights now held in 128 VGPRs (32 hf8 fragments), loaded ONCE per wave straight from
//    a prep-emitted f16 fragment image (L1-resident broadcast) -> no weight LDS at all
//  - layer-3 bias deferred past max reduction into ge_final (max/lrelu commute with
//    per-o constant shift) -> no l=3 bias reads, no per-block epilogue lrelu
//  - 256 cols/wave, grid 512 = exactly 2 blocks/CU at <=256 VGPR (launch_bounds(256,2)),
//    one full occupancy round, weight-load cost amortized over 16 nt
//  - cur[] buffer dropped: nxt packs straight into bf at loop top

#define G_TOT 65536

typedef _Float16 hf2 __attribute__((ext_vector_type(2)));
typedef _Float16 hf4 __attribute__((ext_vector_type(4)));
typedef _Float16 hf8 __attribute__((ext_vector_type(8)));
typedef float float4_ __attribute__((ext_vector_type(4)));

static __device__ __forceinline__ hf2 pkh(float x, float y) {
    return __builtin_bit_cast(hf2, __builtin_amdgcn_cvt_pkrtz(x, y));
}

// ws layout (floats):
//   [0, 8192)       wf16: 16384 f16 weight fragments, frag-major
//                   elem (f*512 + lane*8 + e) = f16(Wa[l][16*mt+(lane&15)][32*pr+16*(e>>2)+4*(lane>>4)+(e&3)])
//                   with f = ((l*4+mt)*2+pr)
//   [16384, 18432)  nbias[b][l][o] fp32 (NEGATED bias)
//   [18432, 18944)  maxenc (uint32 ordered-float), zeroed by prep

__global__ __launch_bounds__(256) void ge_prep(
    const float* __restrict__ feat,
    const float* __restrict__ W0, const float* __restrict__ W1,
    const float* __restrict__ W2, const float* __restrict__ W3,
    float* __restrict__ ws)
{
    const int tid = threadIdx.x;
    const int blk = blockIdx.x;
    __shared__ float lw[64][129];
    __shared__ float x0[2][64];

    if (blk == 8) {
        // maxenc init + f16 fragment image of Wa = W[:,:64] + W[:,64:]
        unsigned* maxenc = (unsigned*)(ws + 18432);
        maxenc[tid] = 0u; maxenc[tid + 256] = 0u;
        _Float16* wf = (_Float16*)ws;
        for (int ci = tid; ci < 8192; ci += 256) {       // ci indexes hf2 chunks
            int f = ci >> 8, ln = (ci >> 2) & 63, h2 = ci & 3;
            int l = f >> 3, mt = (f >> 1) & 3, pr = f & 1;
            int o = (mt << 4) + (ln & 15);
            int c = (pr << 5) + ((h2 >> 1) << 4) + ((ln >> 4) << 2) + ((h2 & 1) << 1);
            const float* Wl = (l == 0) ? W0 : (l == 1) ? W1 : (l == 2) ? W2 : W3;
            float a0 = Wl[o * 128 + c]     + Wl[o * 128 + 64 + c];
            float a1 = Wl[o * 128 + c + 1] + Wl[o * 128 + 64 + c + 1];
            *(hf2*)&wf[ci << 1] = pkh(a0, a1);
        }
        return;
    }

    // blocks 0..7: exact fp32 bias chain for batch b = blk
    const int b = blk;
    if (tid < 64) x0[0][tid] = feat[(size_t)(b * 64 + tid) * G_TOT];
    float* nbias = ws + 16384;
    for (int l = 0; l < 4; ++l) {
        const float* Wl = (l == 0) ? W0 : (l == 1) ? W1 : (l == 2) ? W2 : W3;
        for (int i = tid; i < 64 * 128; i += 256) lw[i >> 7][i & 127] = Wl[i];
        __syncthreads();
        if (tid < 64) {
            const int o = tid;
            const float* src = x0[l & 1];
            float s1 = 0.f, s2 = 0.f;
            for (int c = 0; c < 64; ++c) {
                float xv = src[c];
                s1 += lw[o][c] * xv;
                s2 += lw[o][64 + c] * xv;
            }
            nbias[b * 256 + l * 64 + o] = -s2;          // negated, [b][l][o]
            x0[(l & 1) ^ 1][o] = fmaxf(s1, 0.1f * s1);
        }
        __syncthreads();
    }
}

__global__ __launch_bounds__(256, 2) void ge_main(
    const float* __restrict__ feat,
    const float* __restrict__ ws_wf,
    const float* __restrict__ nbias,
    unsigned* __restrict__ maxenc)
{
    __shared__ float lbias[256];
    __shared__ float blockmax[4][64];
    const int tid = threadIdx.x;
    const int b = blockIdx.x >> 6;      // 64 blocks per batch, 1024 cols each
    const int w = tid >> 6, lane = tid & 63, q = lane >> 4, n = lane & 15;

    lbias[tid] = nbias[(b << 8) + tid];

    // all 4 layers' weight fragments -> 128 VGPRs, read once (L1-broadcast 16 KB)
    hf8 wfr[4][4][2];
    {
        const hf8* wp = (const hf8*)ws_wf;
#pragma unroll
        for (int l = 0; l < 4; ++l)
#pragma unroll
            for (int mt = 0; mt < 4; ++mt)
#pragma unroll
                for (int pr = 0; pr < 2; ++pr)
                    wfr[l][mt][pr] = wp[((((((l << 2) + mt) << 1) + pr)) << 6) + lane];
    }

    const int g0 = ((blockIdx.x & 63) << 10) + (w << 8);   // 256 cols per wave
    const float* Xrow = feat + (size_t)b * 64 * G_TOT + (size_t)(q << 2) * G_TOT;

    float rmax[4][4];
#pragma unroll
    for (int mt = 0; mt < 4; ++mt)
#pragma unroll
        for (int j = 0; j < 4; ++j) rmax[mt][j] = -__builtin_inff();

    float nxt[16];
    {
        int gcol = g0 + n;
#pragma unroll
        for (int kf = 0; kf < 4; ++kf)
#pragma unroll
            for (int r = 0; r < 4; ++r)
                nxt[kf * 4 + r] = Xrow[(size_t)((kf << 4) + r) * G_TOT + gcol];
    }
    __syncthreads();

#pragma unroll 1
    for (int nt = 0; nt < 16; ++nt) {
        // pack current tile (waits on its loads), then immediately issue next tile
        hf4 bf[4];
#pragma unroll
        for (int kf = 0; kf < 4; ++kf) {
            union { hf2 h2[2]; hf4 h4; } u;
            u.h2[0] = pkh(nxt[kf * 4 + 0], nxt[kf * 4 + 1]);
            u.h2[1] = pkh(nxt[kf * 4 + 2], nxt[kf * 4 + 3]);
            bf[kf] = u.h4;
        }
        if (nt < 15) {
            int gcol = g0 + ((nt + 1) << 4) + n;
#pragma unroll
            for (int kf = 0; kf < 4; ++kf)
#pragma unroll
                for (int r = 0; r < 4; ++r)
                    nxt[kf * 4 + r] = Xrow[(size_t)((kf << 4) + r) * G_TOT + gcol];
        }

#pragma unroll
        for (int l = 0; l < 4; ++l) {
            float4_ acc[4];
#pragma unroll
            for (int mt = 0; mt < 4; ++mt) {
                if (l < 3) {    // acc init = -bias (quad-broadcast b128)
                    acc[mt] = *(const float4_*)&lbias[(l << 6) + (mt << 4) + (q << 2)];
                } else {        // layer-3 bias fully deferred to ge_final
                    acc[mt] = float4_{0.f, 0.f, 0.f, 0.f};
                }
            }
#pragma unroll
            for (int mt = 0; mt < 4; ++mt) {
#pragma unroll
                for (int pr = 0; pr < 2; ++pr) {
                    union { hf8 h8; hf4 h4[2]; } ua;
                    ua.h8 = wfr[l][mt][pr];
                    acc[mt] = __builtin_amdgcn_mfma_f32_16x16x16f16(ua.h4[0], bf[(pr << 1) + 0], acc[mt], 0, 0, 0);
                    acc[mt] = __builtin_amdgcn_mfma_f32_16x16x16f16(ua.h4[1], bf[(pr << 1) + 1], acc[mt], 0, 0, 0);
                }
            }
            if (l < 3) {
#pragma unroll
                for (int mt = 0; mt < 4; ++mt) {   // packed-f16 leaky-relu
                    union { hf2 h2[2]; hf4 h4; } u;
                    u.h2[0] = pkh(acc[mt][0], acc[mt][1]);
                    u.h2[1] = pkh(acc[mt][2], acc[mt][3]);
                    hf4 h = u.h4;
                    h = __builtin_elementwise_max(h, h * hf4{(_Float16)0.1f, (_Float16)0.1f, (_Float16)0.1f, (_Float16)0.1f});
                    bf[mt] = h;   // D rows of tile mt == next-layer K-chunk mt
                }
            } else {
                // raw max only; bias + lrelu applied once in ge_final (both commute with max)
#pragma unroll
                for (int mt = 0; mt < 4; ++mt)
#pragma unroll
                    for (int j = 0; j < 4; ++j)
                        rmax[mt][j] = fmaxf(rmax[mt][j], acc[mt][j]);
            }
        }
    }

    // reduce raw max over 16 column-lanes
#pragma unroll
    for (int mt = 0; mt < 4; ++mt)
#pragma unroll
        for (int j = 0; j < 4; ++j) {
            float v = rmax[mt][j];
            v = fmaxf(v, __shfl_xor(v, 1, 64));
            v = fmaxf(v, __shfl_xor(v, 2, 64));
            v = fmaxf(v, __shfl_xor(v, 4, 64));
            v = fmaxf(v, __shfl_xor(v, 8, 64));
            rmax[mt][j] = v;
        }
    if (n == 0) {
#pragma unroll
        for (int mt = 0; mt < 4; ++mt)
#pragma unroll
            for (int j = 0; j < 4; ++j)
                blockmax[w][(mt << 4) + (q << 2) + j] = rmax[mt][j];
    }
    __syncthreads();
    if (tid < 64) {
        float v = fmaxf(fmaxf(blockmax[0][tid], blockmax[1][tid]),
                        fmaxf(blockmax[2][tid], blockmax[3][tid]));
        unsigned s = __float_as_uint(v);
        unsigned enc = (s & 0x80000000u) ? ~s : (s | 0x80000000u);
        atomicMax(&maxenc[b * 64 + tid], enc);
    }
}

__global__ void ge_final(const unsigned* __restrict__ maxenc,
                         const float* __restrict__ nbias,
                         float* __restrict__ out)
{
    int i = threadIdx.x;
    if (i < 512) {
        unsigned u = maxenc[i];
        unsigned s = (u & 0x80000000u) ? (u ^ 0x80000000u) : ~u;
        // deferred layer-3 bias + leaky-relu (both commute with max over G)
        float v = __uint_as_float(s) + nbias[((i >> 6) << 8) + 192 + (i & 63)];
        out[i] = fmaxf(v, 0.1f * v);
    }
}

extern "C" void kernel_launch(void* const* d_in, const int* in_sizes, int n_in,
                              void* d_out, int out_size, void* d_ws, size_t ws_size,
                              hipStream_t stream) {
    const float* feat = (const float*)d_in[0];
    const float* W0 = (const float*)d_in[1];
    const float* W1 = (const float*)d_in[2];
    const float* W2 = (const float*)d_in[3];
    const float* W3 = (const float*)d_in[4];
    float* ws = (float*)d_ws;
    unsigned* maxenc = (unsigned*)(ws + 18432);

    ge_prep<<<9, 256, 0, stream>>>(feat, W0, W1, W2, W3, ws);
    ge_main<<<512, 256, 0, stream>>>(feat, ws, ws + 16384, maxenc);
    ge_final<<<1, 512, 0, stream>>>(maxenc, ws + 16384, (float*)d_out);
}